// Round 2
// baseline (253.320 us; speedup 1.0000x reference)
//
#include <hip/hip_runtime.h>
#include <math.h>
#include <stdint.h>

#define SEQ  2048
#define LOG2E 1.4426950408889634f

typedef __attribute__((ext_vector_type(4))) float f32x4;
typedef __attribute__((ext_vector_type(16))) float f32x16;
typedef __attribute__((ext_vector_type(8))) short bf16x8;

template <int V> struct IC { static constexpr int value = V; };

// pack two fp32 -> bf16x2 dword via v_perm (round-half-up; ties-only diff vs RNE)
__device__ __forceinline__ unsigned packbf(float a, float b) {
    return __builtin_amdgcn_perm(__float_as_uint(b) + 0x8000u,
                                 __float_as_uint(a) + 0x8000u, 0x07060302u);
}

// ---------------------------------------------------------------------------
// QKV GEMM with FUSED fp32->bf16 convert. C = x(M,512) @ W(N,512)^T + bias,
// N=1536 (Q|K|V), grid (12,64), 128x128 tiles, BK=32, VGPR-staged LDS.
// Frag-linear outputs (exact MFMA fragment image; attn reads straight from L2):
//   Q'/K': [bh][q32tile(64)][kt(4)][lane(64)][8]   (TR orientation; Q *LOG2E)
//   V'   : [bh][j64tile(32)][dg*4+p(8)][lane(64)][8]
// ---------------------------------------------------------------------------
__global__ __launch_bounds__(256, 3) void qkv_kernel(
    const float* __restrict__ xf, const float* __restrict__ wqf,
    const float* __restrict__ wkf, const float* __restrict__ wvf,
    const float* __restrict__ bq, const float* __restrict__ bk,
    const float* __restrict__ bv,
    unsigned short* __restrict__ Qw, unsigned short* __restrict__ Kw,
    unsigned short* __restrict__ VTw)
{
    __shared__ __align__(16) unsigned short smem[8192];   // As 4096 | Bs 4096
    unsigned short* As = smem;
    unsigned short* Bs = smem + 4096;

    const int t = threadIdx.x;
    const int w = t >> 6, lane = t & 63, quad = (t >> 4) & 3, l15 = t & 15;
    const int wr = w >> 1, wc = w & 1;
    const int m0 = blockIdx.y * 128;
    const int n0 = blockIdx.x * 128;
    const int which = n0 >> 9;                 // 0=Q 1=K 2=V
    const float* wbase = which == 0 ? wqf : (which == 1 ? wkf : wvf);
    const int nrow = n0 & 511;

    const int ar = t >> 2, akq = t & 3;
    const float* ax = xf + (size_t)(m0 + ar) * 512 + akq * 8;
    const float* bx = wbase + (size_t)(nrow + ar) * 512 + akq * 8;
    const int lws = (ar & 15) | (akq << 4);
    const int off0 = (ar >> 4) * 512 + lws * 8;
    const int off1 = off0 + 4 * 512;

    f32x4 acc[4][4];
#pragma unroll
    for (int mt = 0; mt < 4; ++mt)
#pragma unroll
        for (int nt = 0; nt < 4; ++nt) acc[mt][nt] = (f32x4){0.f, 0.f, 0.f, 0.f};

    float4 ra[4], rb[4];
    auto loadt = [&](int k0) {
        ra[0] = *(const float4*)(ax + k0);
        ra[1] = *(const float4*)(ax + k0 + 4);
        ra[2] = *(const float4*)(ax + 32768 + k0);
        ra[3] = *(const float4*)(ax + 32768 + k0 + 4);
        rb[0] = *(const float4*)(bx + k0);
        rb[1] = *(const float4*)(bx + k0 + 4);
        rb[2] = *(const float4*)(bx + 32768 + k0);
        rb[3] = *(const float4*)(bx + 32768 + k0 + 4);
    };
    auto writet = [&]() {
        uint4 p;
        p.x = packbf(ra[0].x, ra[0].y); p.y = packbf(ra[0].z, ra[0].w);
        p.z = packbf(ra[1].x, ra[1].y); p.w = packbf(ra[1].z, ra[1].w);
        *(uint4*)(As + off0) = p;
        p.x = packbf(ra[2].x, ra[2].y); p.y = packbf(ra[2].z, ra[2].w);
        p.z = packbf(ra[3].x, ra[3].y); p.w = packbf(ra[3].z, ra[3].w);
        *(uint4*)(As + off1) = p;
        p.x = packbf(rb[0].x, rb[0].y); p.y = packbf(rb[0].z, rb[0].w);
        p.z = packbf(rb[1].x, rb[1].y); p.w = packbf(rb[1].z, rb[1].w);
        *(uint4*)(Bs + off0) = p;
        p.x = packbf(rb[2].x, rb[2].y); p.y = packbf(rb[2].z, rb[2].w);
        p.z = packbf(rb[3].x, rb[3].y); p.w = packbf(rb[3].z, rb[3].w);
        *(uint4*)(Bs + off1) = p;
    };

    loadt(0);
    auto kloop = [&](auto TRC) {
        constexpr int TR = decltype(TRC)::value;
        for (int ki = 0; ki < 16; ++ki) {
            writet();
            if (ki < 15) loadt((ki + 1) * 32);
            __syncthreads();
            bf16x8 af[4], bfr[4];
#pragma unroll
            for (int mt = 0; mt < 4; ++mt)
                af[mt] = *(const bf16x8*)(As + ((wr * 4 + mt) * 64 + lane) * 8);
#pragma unroll
            for (int nt = 0; nt < 4; ++nt)
                bfr[nt] = *(const bf16x8*)(Bs + ((wc * 4 + nt) * 64 + lane) * 8);
#pragma unroll
            for (int mt = 0; mt < 4; ++mt)
#pragma unroll
                for (int nt = 0; nt < 4; ++nt) {
                    if (TR)
                        acc[mt][nt] = __builtin_amdgcn_mfma_f32_16x16x32_bf16(
                            bfr[nt], af[mt], acc[mt][nt], 0, 0, 0);
                    else
                        acc[mt][nt] = __builtin_amdgcn_mfma_f32_16x16x32_bf16(
                            af[mt], bfr[nt], acc[mt][nt], 0, 0, 0);
                }
            if (ki < 15) __syncthreads();
        }
    };
    if (which < 2) kloop(IC<1>{});
    else           kloop(IC<0>{});

    if (which == 2) {
        // V: normal orientation -> frag-linear V'
#pragma unroll
        for (int nt = 0; nt < 4; ++nt) {
            const int n = n0 + wc * 64 + nt * 16 + l15;
            const float bias = bv[n & 511];
            const int h = (n >> 6) & 7, d = n & 63;
#pragma unroll
            for (int mt = 0; mt < 4; ++mt) {
                const int mb = m0 + wr * 64 + mt * 16 + quad * 4;
                const int bi = mb >> 11, ns = mb & 2047;
                const int bhl = bi * 8 + h;
                const f32x4 v = acc[mt][nt];
                uint2 pk;
                pk.x = packbf(v[0] + bias, v[1] + bias);
                pk.y = packbf(v[2] + bias, v[3] + bias);
                const size_t off =
                    ((size_t)(bhl * 32 + (ns >> 6)) * 8 + ((d >> 5) << 2) +
                     ((ns >> 4) & 3)) * 512 +
                    ((d & 31) << 3) + ((ns & 8) << 5) + (ns & 7);
                *(uint2*)(VTw + off) = pk;
            }
        }
    } else {
        // Q/K: TR orientation -> frag-linear Q'/K'
        const float sc = which ? 1.f : LOG2E;
        const float* bpt = which ? bk : bq;
        unsigned short* base = which ? Kw : Qw;
#pragma unroll
        for (int nt = 0; nt < 4; ++nt) {
            const int nb = n0 + wc * 64 + nt * 16 + quad * 4;   // d base
            const f32x4 bvv = *(const f32x4*)(bpt + (nb & 511));
            const int h = (nb >> 6) & 7, d0 = nb & 63;
#pragma unroll
            for (int mt = 0; mt < 4; ++mt) {
                const int nsg = m0 + wr * 64 + mt * 16 + l15;   // ns (col=l15)
                const int bi = nsg >> 11, ns = nsg & 2047;
                const int bhl = bi * 8 + h;
                const f32x4 v = acc[mt][nt];
                uint2 pk;
                pk.x = packbf((v[0] + bvv[0]) * sc, (v[1] + bvv[1]) * sc);
                pk.y = packbf((v[2] + bvv[2]) * sc, (v[3] + bvv[3]) * sc);
                const size_t off =
                    ((size_t)(bhl * 64 + (ns >> 5)) * 4 + (d0 >> 4)) * 512 +
                    ((d0 & 8) << 5) + ((ns & 31) << 3) + (d0 & 7);
                *(uint2*)(base + off) = pk;
            }
        }
    }
}

// ---------------------------------------------------------------------------
// Out-projection GEMM: out = Owb(M,512) @ Wp(512,512)^T + bp, fp32 out.
// 128x64 tiles, grid (8,64); Wp converted inline.
// ---------------------------------------------------------------------------
__global__ __launch_bounds__(256, 3) void outproj_kernel(
    const unsigned short* __restrict__ Aw, const float* __restrict__ wpf,
    const float* __restrict__ bp, float* __restrict__ out)
{
    __shared__ __align__(16) unsigned short smem[6144];   // As 4096 | Bs 2048
    unsigned short* As = smem;
    unsigned short* Bs = smem + 4096;

    const int t = threadIdx.x;
    const int w = t >> 6, lane = t & 63, quad = (t >> 4) & 3, l15 = t & 15;
    const int wr = w >> 1, wc = w & 1;
    const int m0 = blockIdx.y * 128;
    const int n0 = blockIdx.x * 64;

    const int ar = t >> 2, akq = t & 3;
    const unsigned short* ap = Aw + (size_t)(m0 + ar) * 512 + akq * 8;
    const float* bx = wpf + (size_t)(n0 + ar) * 512 + akq * 8;
    const int lws = (ar & 15) | (akq << 4);
    const int off0 = (ar >> 4) * 512 + lws * 8;
    const int off1 = off0 + 4 * 512;
    const int boff = (ar >> 4) * 512 + lws * 8;

    f32x4 acc[4][2];
#pragma unroll
    for (int mt = 0; mt < 4; ++mt)
#pragma unroll
        for (int nt = 0; nt < 2; ++nt) acc[mt][nt] = (f32x4){0.f, 0.f, 0.f, 0.f};

    uint4 ra0, ra1;
    float4 rb0, rb1;
    auto loadt = [&](int k0) {
        ra0 = *(const uint4*)(ap + k0);
        ra1 = *(const uint4*)(ap + 32768 + k0);
        rb0 = *(const float4*)(bx + k0);
        rb1 = *(const float4*)(bx + k0 + 4);
    };
    auto writet = [&]() {
        *(uint4*)(As + off0) = ra0;
        *(uint4*)(As + off1) = ra1;
        uint4 p;
        p.x = packbf(rb0.x, rb0.y); p.y = packbf(rb0.z, rb0.w);
        p.z = packbf(rb1.x, rb1.y); p.w = packbf(rb1.z, rb1.w);
        *(uint4*)(Bs + boff) = p;
    };

    loadt(0);
    for (int ki = 0; ki < 16; ++ki) {
        writet();
        if (ki < 15) loadt((ki + 1) * 32);
        __syncthreads();
        bf16x8 af[4], bfr[2];
#pragma unroll
        for (int mt = 0; mt < 4; ++mt)
            af[mt] = *(const bf16x8*)(As + ((wr * 4 + mt) * 64 + lane) * 8);
#pragma unroll
        for (int nt = 0; nt < 2; ++nt)
            bfr[nt] = *(const bf16x8*)(Bs + ((wc * 2 + nt) * 64 + lane) * 8);
#pragma unroll
        for (int mt = 0; mt < 4; ++mt)
#pragma unroll
            for (int nt = 0; nt < 2; ++nt)
                acc[mt][nt] = __builtin_amdgcn_mfma_f32_16x16x32_bf16(
                    af[mt], bfr[nt], acc[mt][nt], 0, 0, 0);
        if (ki < 15) __syncthreads();
    }

#pragma unroll
    for (int nt = 0; nt < 2; ++nt) {
        const int n = n0 + wc * 32 + nt * 16 + l15;
        const float bias = bp[n];
#pragma unroll
        for (int mt = 0; mt < 4; ++mt) {
            const int mb = m0 + wr * 64 + mt * 16 + quad * 4;
            const f32x4 v = acc[mt][nt];
#pragma unroll
            for (int r = 0; r < 4; ++r)
                out[(size_t)(mb + r) * 512 + n] = v[r] + bias;
        }
    }
}

// ---------------------------------------------------------------------------
// bf16 32x32x16-MFMA flash attention — zero LDS/barriers in the K-loop.
// Grid (32,16) x 512 threads = 8 waves/block, 2 blocks/CU, ~4 waves/SIMD.
// Wave w: qi = w>>1 picks one 32-q group, jh = w&1 picks the 32-key half of
// each 64-key tile.
// SOFTWARE PIPELINE (R2): iteration t computes S[t+1] (MFMA pipe, depends
// only on prefetched K[t+1] + Q) CONCURRENTLY with exp/pack of S[t] (VALU
// pipe) and PV[t]. Two st accumulators ping-pong with STATIC roles (2-step
// unrolled body; runtime-indexed would go to scratch). K prefetch distance 2.
// This breaks the per-iteration serial chain (S->exp->pack->shfl->PV) that
// left both pipes <45% busy at 4 waves/SIMD in R1.
// End: one LDS merge adds (O,l) across the jh pair; jh=0 stores.
// att = softmax(unscaled)/sqrt(512)
// ---------------------------------------------------------------------------
__global__ __launch_bounds__(512, 4) void attn_kernel(
    const unsigned short* __restrict__ Qf, const unsigned short* __restrict__ Kf,
    const unsigned short* __restrict__ Vf, unsigned short* __restrict__ Ow)
{
    __shared__ float cb[8448];   // O partials 8192 + l partials 256
    const int t = threadIdx.x;
    const int w = t >> 6, lane = t & 63;
    const int l31 = lane & 31, hlf = lane >> 5;
    const int qi = w >> 1, jh = w & 1;

    const int bh = blockIdx.x;          // bh%8 pins one (b,h) to one XCD
    const int qblk = blockIdx.y;        // 0..15
    const int q0 = qblk * 128;

    const unsigned short* Kp = Kf + (size_t)bh * 131072 + (jh * 4) * 512 + lane * 8;
    const unsigned short* Vp = Vf + (size_t)bh * 131072 + lane * 8;

    const int qgg = qblk * 4 + qi;
    const unsigned short* Qp = Qf + ((size_t)(bh * 64 + qgg) * 4) * 512 + lane * 8;
    bf16x8 qf[4];
#pragma unroll
    for (int kt = 0; kt < 4; ++kt)
        qf[kt] = *(const bf16x8*)(Qp + kt * 512);

    f32x16 zero;
#pragma unroll
    for (int r = 0; r < 16; ++r) zero[r] = 0.f;

    float lpart = 0.f;
    f32x16 Ot[2];
    Ot[0] = zero; Ot[1] = zero;

    // ---- prologue: S[0], then kc <- K[1] ----
    bf16x8 kc[4];
#pragma unroll
    for (int c = 0; c < 4; ++c)
        kc[c] = *(const bf16x8*)(Kp + c * 512);

    f32x16 stA = zero, stB = zero;
#pragma unroll
    for (int kt = 0; kt < 4; ++kt)
        stA = __builtin_amdgcn_mfma_f32_32x32x16_bf16(kc[kt], qf[kt], stA, 0, 0, 0);
#pragma unroll
    for (int c = 0; c < 4; ++c)
        kc[c] = *(const bf16x8*)(Kp + 4096 + c * 512);

    // stc: ready S-acc for tile jt; stn: S[jt+1] computed this iteration.
    auto step = [&](f32x16& stc, f32x16& stn, int jt) {
        // V frags for tile jt (consumed by PV at the end -> latency hidden)
        bf16x8 vc[4];
#pragma unroll
        for (int dg = 0; dg < 2; ++dg)
#pragma unroll
            for (int p = 0; p < 2; ++p)
                vc[dg * 2 + p] = *(const bf16x8*)(
                    Vp + (size_t)jt * 4096 + (dg * 4 + jh * 2 + p) * 512);

        // S[jt+1] — independent of stc; matrix pipe runs under the VALU below
        stn = zero;
        __builtin_amdgcn_s_setprio(1);
#pragma unroll
        for (int kt = 0; kt < 4; ++kt)
            stn = __builtin_amdgcn_mfma_f32_32x32x16_bf16(kc[kt], qf[kt], stn, 0, 0, 0);
        __builtin_amdgcn_s_setprio(0);

        // K prefetch, distance 2
        const int jn = (jt < 30) ? jt + 2 : 31;
#pragma unroll
        for (int c = 0; c < 4; ++c)
            kc[c] = *(const bf16x8*)(Kp + (size_t)jn * 4096 + c * 512);

        // p = 2^s for tile jt (no max subtraction; logits bounded)
#pragma unroll
        for (int r = 0; r < 16; ++r)
            stc[r] = __builtin_amdgcn_exp2f(stc[r]);
        {
            float s01 = stc[0] + stc[1],   s23 = stc[2] + stc[3];
            float s45 = stc[4] + stc[5],   s67 = stc[6] + stc[7];
            float s89 = stc[8] + stc[9],   sAB = stc[10] + stc[11];
            float sCD = stc[12] + stc[13], sEF = stc[14] + stc[15];
            lpart += ((s01 + s23) + (s45 + s67)) + ((s89 + sAB) + (sCD + sEF));
        }

        // P^T -> B-frag (lane-half exchange only), then PV
#pragma unroll
        for (int p = 0; p < 2; ++p) {
            const int r0 = p * 8;
            const unsigned a0 = packbf(stc[r0 + 0], stc[r0 + 1]);
            const unsigned a1 = packbf(stc[r0 + 2], stc[r0 + 3]);
            const unsigned b0 = packbf(stc[r0 + 4], stc[r0 + 5]);
            const unsigned b1 = packbf(stc[r0 + 6], stc[r0 + 7]);
            const unsigned ta0 = (unsigned)__shfl_xor((int)a0, 32);
            const unsigned ta1 = (unsigned)__shfl_xor((int)a1, 32);
            const unsigned tb0 = (unsigned)__shfl_xor((int)b0, 32);
            const unsigned tb1 = (unsigned)__shfl_xor((int)b1, 32);
            union { unsigned u[4]; bf16x8 v; } pb;
            pb.u[0] = hlf ? tb0 : a0;
            pb.u[1] = hlf ? tb1 : a1;
            pb.u[2] = hlf ? b0 : ta0;
            pb.u[3] = hlf ? b1 : ta1;
            __builtin_amdgcn_s_setprio(1);
            Ot[0] = __builtin_amdgcn_mfma_f32_32x32x16_bf16(vc[0 + p], pb.v, Ot[0], 0, 0, 0);
            Ot[1] = __builtin_amdgcn_mfma_f32_32x32x16_bf16(vc[2 + p], pb.v, Ot[1], 0, 0, 0);
            __builtin_amdgcn_s_setprio(0);
        }
    };

    for (int jt = 0; jt < 32; jt += 2) {
        step(stA, stB, jt);        // PV[jt],   computes S[jt+1] into stB
        step(stB, stA, jt + 1);    // PV[jt+1], computes S[jt+2] into stA
    }

    // ---- merge (O, l) across the jh pair; jh=0 stores ----
    if (jh == 1) {
#pragma unroll
        for (int dg = 0; dg < 2; ++dg) {
            const int cidx = (qi * 2 + dg) * 4;
#pragma unroll
            for (int k = 0; k < 4; ++k) {
                float4 v = make_float4(
                    Ot[dg][k * 4 + 0], Ot[dg][k * 4 + 1],
                    Ot[dg][k * 4 + 2], Ot[dg][k * 4 + 3]);
                *(float4*)(cb + (cidx + k) * 256 + lane * 4) = v;
            }
        }
        cb[8192 + qi * 64 + lane] = lpart;
    }
    __syncthreads();
    if (jh == 0) {
        const int bi = bh >> 3, h = bh & 7;
#pragma unroll
        for (int dg = 0; dg < 2; ++dg) {
            const int cidx = (qi * 2 + dg) * 4;
#pragma unroll
            for (int k = 0; k < 4; ++k) {
                const float4 v = *(const float4*)(cb + (cidx + k) * 256 + lane * 4);
                Ot[dg][k * 4 + 0] += v.x;
                Ot[dg][k * 4 + 1] += v.y;
                Ot[dg][k * 4 + 2] += v.z;
                Ot[dg][k * 4 + 3] += v.w;
            }
        }
        float lv = lpart + cb[8192 + qi * 64 + lane];
        lv += __shfl_xor(lv, 32);
        const float inv = 1.0f / (lv * 22.627416997969522f);

        const int ns = q0 + qi * 32 + l31;
        unsigned short* dst = Ow + ((size_t)bi * SEQ + ns) * 512 + h * 64 + hlf * 4;
#pragma unroll
        for (int dg = 0; dg < 2; ++dg)
#pragma unroll
            for (int rb2 = 0; rb2 < 4; ++rb2) {
                uint2 pk;
                pk.x = packbf(Ot[dg][rb2 * 4 + 0] * inv,
                              Ot[dg][rb2 * 4 + 1] * inv);
                pk.y = packbf(Ot[dg][rb2 * 4 + 2] * inv,
                              Ot[dg][rb2 * 4 + 3] * inv);
                *(uint2*)(dst + dg * 32 + rb2 * 8) = pk;
            }
    }
}

// ---------------------------------------------------------------------------
extern "C" void kernel_launch(void* const* d_in, const int* in_sizes, int n_in,
                              void* d_out, int out_size, void* d_ws, size_t ws_size,
                              hipStream_t stream)
{
    const float* x  = (const float*)d_in[0];
    const float* Wq = (const float*)d_in[1];
    const float* bq = (const float*)d_in[2];
    const float* Wk = (const float*)d_in[3];
    const float* bk = (const float*)d_in[4];
    const float* Wv = (const float*)d_in[5];
    const float* bv = (const float*)d_in[6];
    const float* Wp = (const float*)d_in[7];
    const float* bp = (const float*)d_in[8];

    unsigned short* ws = (unsigned short*)d_ws;
    unsigned short* Qw  = ws;                  // Q' frag-linear, *log2e (8 MB)
    unsigned short* Kw  = Qw + 4194304;        // K' frag-linear
    unsigned short* VTw = Kw + 4194304;        // V' frag-linear
    unsigned short* Owb = VTw + 4194304;       // [b][ns][512] bf16

    qkv_kernel<<<dim3(12, 64), 256, 0, stream>>>(
        x, Wq, Wk, Wv, bq, bk, bv, Qw, Kw, VTw);
    attn_kernel<<<dim3(32, 16), 512, 0, stream>>>(Qw, Kw, VTw, Owb);
    outproj_kernel<<<dim3(8, 64), 256, 0, stream>>>(Owb, Wp, bp, (float*)d_out);
}

// Round 3
// 163.108 us; speedup vs baseline: 1.5531x; 1.5531x over previous
//
#include <hip/hip_runtime.h>
#include <math.h>
#include <stdint.h>

#define SEQ  2048
#define LOG2E 1.4426950408889634f

typedef __attribute__((ext_vector_type(4))) float f32x4;
typedef __attribute__((ext_vector_type(16))) float f32x16;
typedef __attribute__((ext_vector_type(8))) short bf16x8;

template <int V> struct IC { static constexpr int value = V; };

// pack two fp32 -> bf16x2 dword via v_perm (round-half-up; ties-only diff vs RNE)
__device__ __forceinline__ unsigned packbf(float a, float b) {
    return __builtin_amdgcn_perm(__float_as_uint(b) + 0x8000u,
                                 __float_as_uint(a) + 0x8000u, 0x07060302u);
}

// ---------------------------------------------------------------------------
// QKV GEMM with FUSED fp32->bf16 convert. C = x(M,512) @ W(N,512)^T + bias,
// N=1536 (Q|K|V), grid (12,64), 128x128 tiles, BK=32, VGPR-staged LDS.
// Frag-linear outputs (exact MFMA fragment image; attn reads straight from L2):
//   Q'/K': [bh][q32tile(64)][kt(4)][lane(64)][8]   (TR orientation; Q *LOG2E)
//   V'   : [bh][j64tile(32)][dg*4+p(8)][lane(64)][8]
// ---------------------------------------------------------------------------
__global__ __launch_bounds__(256, 3) void qkv_kernel(
    const float* __restrict__ xf, const float* __restrict__ wqf,
    const float* __restrict__ wkf, const float* __restrict__ wvf,
    const float* __restrict__ bq, const float* __restrict__ bk,
    const float* __restrict__ bv,
    unsigned short* __restrict__ Qw, unsigned short* __restrict__ Kw,
    unsigned short* __restrict__ VTw)
{
    __shared__ __align__(16) unsigned short smem[8192];   // As 4096 | Bs 4096
    unsigned short* As = smem;
    unsigned short* Bs = smem + 4096;

    const int t = threadIdx.x;
    const int w = t >> 6, lane = t & 63, quad = (t >> 4) & 3, l15 = t & 15;
    const int wr = w >> 1, wc = w & 1;
    const int m0 = blockIdx.y * 128;
    const int n0 = blockIdx.x * 128;
    const int which = n0 >> 9;                 // 0=Q 1=K 2=V
    const float* wbase = which == 0 ? wqf : (which == 1 ? wkf : wvf);
    const int nrow = n0 & 511;

    const int ar = t >> 2, akq = t & 3;
    const float* ax = xf + (size_t)(m0 + ar) * 512 + akq * 8;
    const float* bx = wbase + (size_t)(nrow + ar) * 512 + akq * 8;
    const int lws = (ar & 15) | (akq << 4);
    const int off0 = (ar >> 4) * 512 + lws * 8;
    const int off1 = off0 + 4 * 512;

    f32x4 acc[4][4];
#pragma unroll
    for (int mt = 0; mt < 4; ++mt)
#pragma unroll
        for (int nt = 0; nt < 4; ++nt) acc[mt][nt] = (f32x4){0.f, 0.f, 0.f, 0.f};

    float4 ra[4], rb[4];
    auto loadt = [&](int k0) {
        ra[0] = *(const float4*)(ax + k0);
        ra[1] = *(const float4*)(ax + k0 + 4);
        ra[2] = *(const float4*)(ax + 32768 + k0);
        ra[3] = *(const float4*)(ax + 32768 + k0 + 4);
        rb[0] = *(const float4*)(bx + k0);
        rb[1] = *(const float4*)(bx + k0 + 4);
        rb[2] = *(const float4*)(bx + 32768 + k0);
        rb[3] = *(const float4*)(bx + 32768 + k0 + 4);
    };
    auto writet = [&]() {
        uint4 p;
        p.x = packbf(ra[0].x, ra[0].y); p.y = packbf(ra[0].z, ra[0].w);
        p.z = packbf(ra[1].x, ra[1].y); p.w = packbf(ra[1].z, ra[1].w);
        *(uint4*)(As + off0) = p;
        p.x = packbf(ra[2].x, ra[2].y); p.y = packbf(ra[2].z, ra[2].w);
        p.z = packbf(ra[3].x, ra[3].y); p.w = packbf(ra[3].z, ra[3].w);
        *(uint4*)(As + off1) = p;
        p.x = packbf(rb[0].x, rb[0].y); p.y = packbf(rb[0].z, rb[0].w);
        p.z = packbf(rb[1].x, rb[1].y); p.w = packbf(rb[1].z, rb[1].w);
        *(uint4*)(Bs + off0) = p;
        p.x = packbf(rb[2].x, rb[2].y); p.y = packbf(rb[2].z, rb[2].w);
        p.z = packbf(rb[3].x, rb[3].y); p.w = packbf(rb[3].z, rb[3].w);
        *(uint4*)(Bs + off1) = p;
    };

    loadt(0);
    auto kloop = [&](auto TRC) {
        constexpr int TR = decltype(TRC)::value;
        for (int ki = 0; ki < 16; ++ki) {
            writet();
            if (ki < 15) loadt((ki + 1) * 32);
            __syncthreads();
            bf16x8 af[4], bfr[4];
#pragma unroll
            for (int mt = 0; mt < 4; ++mt)
                af[mt] = *(const bf16x8*)(As + ((wr * 4 + mt) * 64 + lane) * 8);
#pragma unroll
            for (int nt = 0; nt < 4; ++nt)
                bfr[nt] = *(const bf16x8*)(Bs + ((wc * 4 + nt) * 64 + lane) * 8);
#pragma unroll
            for (int mt = 0; mt < 4; ++mt)
#pragma unroll
                for (int nt = 0; nt < 4; ++nt) {
                    if (TR)
                        acc[mt][nt] = __builtin_amdgcn_mfma_f32_16x16x32_bf16(
                            bfr[nt], af[mt], acc[mt][nt], 0, 0, 0);
                    else
                        acc[mt][nt] = __builtin_amdgcn_mfma_f32_16x16x32_bf16(
                            af[mt], bfr[nt], acc[mt][nt], 0, 0, 0);
                }
            if (ki < 15) __syncthreads();
        }
    };
    if (which < 2) kloop(IC<1>{});
    else           kloop(IC<0>{});

    if (which == 2) {
        // V: normal orientation -> frag-linear V'
#pragma unroll
        for (int nt = 0; nt < 4; ++nt) {
            const int n = n0 + wc * 64 + nt * 16 + l15;
            const float bias = bv[n & 511];
            const int h = (n >> 6) & 7, d = n & 63;
#pragma unroll
            for (int mt = 0; mt < 4; ++mt) {
                const int mb = m0 + wr * 64 + mt * 16 + quad * 4;
                const int bi = mb >> 11, ns = mb & 2047;
                const int bhl = bi * 8 + h;
                const f32x4 v = acc[mt][nt];
                uint2 pk;
                pk.x = packbf(v[0] + bias, v[1] + bias);
                pk.y = packbf(v[2] + bias, v[3] + bias);
                const size_t off =
                    ((size_t)(bhl * 32 + (ns >> 6)) * 8 + ((d >> 5) << 2) +
                     ((ns >> 4) & 3)) * 512 +
                    ((d & 31) << 3) + ((ns & 8) << 5) + (ns & 7);
                *(uint2*)(VTw + off) = pk;
            }
        }
    } else {
        // Q/K: TR orientation -> frag-linear Q'/K'
        const float sc = which ? 1.f : LOG2E;
        const float* bpt = which ? bk : bq;
        unsigned short* base = which ? Kw : Qw;
#pragma unroll
        for (int nt = 0; nt < 4; ++nt) {
            const int nb = n0 + wc * 64 + nt * 16 + quad * 4;   // d base
            const f32x4 bvv = *(const f32x4*)(bpt + (nb & 511));
            const int h = (nb >> 6) & 7, d0 = nb & 63;
#pragma unroll
            for (int mt = 0; mt < 4; ++mt) {
                const int nsg = m0 + wr * 64 + mt * 16 + l15;   // ns (col=l15)
                const int bi = nsg >> 11, ns = nsg & 2047;
                const int bhl = bi * 8 + h;
                const f32x4 v = acc[mt][nt];
                uint2 pk;
                pk.x = packbf((v[0] + bvv[0]) * sc, (v[1] + bvv[1]) * sc);
                pk.y = packbf((v[2] + bvv[2]) * sc, (v[3] + bvv[3]) * sc);
                const size_t off =
                    ((size_t)(bhl * 64 + (ns >> 5)) * 4 + (d0 >> 4)) * 512 +
                    ((d0 & 8) << 5) + ((ns & 31) << 3) + (d0 & 7);
                *(uint2*)(base + off) = pk;
            }
        }
    }
}

// ---------------------------------------------------------------------------
// Out-projection GEMM: out = Owb(M,512) @ Wp(512,512)^T + bp, fp32 out.
// 128x64 tiles, grid (8,64); Wp converted inline.
// ---------------------------------------------------------------------------
__global__ __launch_bounds__(256, 3) void outproj_kernel(
    const unsigned short* __restrict__ Aw, const float* __restrict__ wpf,
    const float* __restrict__ bp, float* __restrict__ out)
{
    __shared__ __align__(16) unsigned short smem[6144];   // As 4096 | Bs 2048
    unsigned short* As = smem;
    unsigned short* Bs = smem + 4096;

    const int t = threadIdx.x;
    const int w = t >> 6, lane = t & 63, quad = (t >> 4) & 3, l15 = t & 15;
    const int wr = w >> 1, wc = w & 1;
    const int m0 = blockIdx.y * 128;
    const int n0 = blockIdx.x * 64;

    const int ar = t >> 2, akq = t & 3;
    const unsigned short* ap = Aw + (size_t)(m0 + ar) * 512 + akq * 8;
    const float* bx = wpf + (size_t)(n0 + ar) * 512 + akq * 8;
    const int lws = (ar & 15) | (akq << 4);
    const int off0 = (ar >> 4) * 512 + lws * 8;
    const int off1 = off0 + 4 * 512;
    const int boff = (ar >> 4) * 512 + lws * 8;

    f32x4 acc[4][2];
#pragma unroll
    for (int mt = 0; mt < 4; ++mt)
#pragma unroll
        for (int nt = 0; nt < 2; ++nt) acc[mt][nt] = (f32x4){0.f, 0.f, 0.f, 0.f};

    uint4 ra0, ra1;
    float4 rb0, rb1;
    auto loadt = [&](int k0) {
        ra0 = *(const uint4*)(ap + k0);
        ra1 = *(const uint4*)(ap + 32768 + k0);
        rb0 = *(const float4*)(bx + k0);
        rb1 = *(const float4*)(bx + k0 + 4);
    };
    auto writet = [&]() {
        *(uint4*)(As + off0) = ra0;
        *(uint4*)(As + off1) = ra1;
        uint4 p;
        p.x = packbf(rb0.x, rb0.y); p.y = packbf(rb0.z, rb0.w);
        p.z = packbf(rb1.x, rb1.y); p.w = packbf(rb1.z, rb1.w);
        *(uint4*)(Bs + boff) = p;
    };

    loadt(0);
    for (int ki = 0; ki < 16; ++ki) {
        writet();
        if (ki < 15) loadt((ki + 1) * 32);
        __syncthreads();
        bf16x8 af[4], bfr[2];
#pragma unroll
        for (int mt = 0; mt < 4; ++mt)
            af[mt] = *(const bf16x8*)(As + ((wr * 4 + mt) * 64 + lane) * 8);
#pragma unroll
        for (int nt = 0; nt < 2; ++nt)
            bfr[nt] = *(const bf16x8*)(Bs + ((wc * 2 + nt) * 64 + lane) * 8);
#pragma unroll
        for (int mt = 0; mt < 4; ++mt)
#pragma unroll
            for (int nt = 0; nt < 2; ++nt)
                acc[mt][nt] = __builtin_amdgcn_mfma_f32_16x16x32_bf16(
                    af[mt], bfr[nt], acc[mt][nt], 0, 0, 0);
        if (ki < 15) __syncthreads();
    }

#pragma unroll
    for (int nt = 0; nt < 2; ++nt) {
        const int n = n0 + wc * 32 + nt * 16 + l15;
        const float bias = bp[n];
#pragma unroll
        for (int mt = 0; mt < 4; ++mt) {
            const int mb = m0 + wr * 64 + mt * 16 + quad * 4;
            const f32x4 v = acc[mt][nt];
#pragma unroll
            for (int r = 0; r < 4; ++r)
                out[(size_t)(mb + r) * 512 + n] = v[r] + bias;
        }
    }
}

// ---------------------------------------------------------------------------
// bf16 32x32x16-MFMA flash attention — zero LDS/barriers in the K-loop.
// Grid (32,16) x 512 threads = 8 waves/block, 2 blocks/CU, ~4 waves/SIMD.
// Wave w: qi = w>>1 picks one 32-q group, jh = w&1 picks the 32-key half of
// each 64-key tile. (R2's 2-deep S pipeline spilled to scratch at the
// 128-VGPR/wave cap: WRITE_SIZE 8->232 MB. Reverted to R1 skeleton.)
// R3: P-frag construction via T12 — v_cvt_pk_bf16_f32 (1 instr, RNE) +
// v_permlane32_swap_b32 (1 instr fills two frag words): 6 instrs/p-slice
// replacing 20 (4x 3-instr pack + 4 shfl_xor DS-ops + 4 cndmask). Cuts
// ~28 VALU/DS instrs per tile per wave and shortens the exp->PV chain.
// End: one LDS merge adds (O,l) across the jh pair; jh=0 stores.
// att = softmax(unscaled)/sqrt(512)
// ---------------------------------------------------------------------------
__global__ __launch_bounds__(512, 4) void attn_kernel(
    const unsigned short* __restrict__ Qf, const unsigned short* __restrict__ Kf,
    const unsigned short* __restrict__ Vf, unsigned short* __restrict__ Ow)
{
    __shared__ float cb[8448];   // O partials 8192 + l partials 256
    const int t = threadIdx.x;
    const int w = t >> 6, lane = t & 63;
    const int l31 = lane & 31, hlf = lane >> 5;
    const int qi = w >> 1, jh = w & 1;

    const int bh = blockIdx.x;          // bh%8 pins one (b,h) to one XCD
    const int qblk = blockIdx.y;        // 0..15
    const int q0 = qblk * 128;

    const unsigned short* Kp = Kf + (size_t)bh * 131072 + (jh * 4) * 512 + lane * 8;
    const unsigned short* Vp = Vf + (size_t)bh * 131072 + lane * 8;

    const int qgg = qblk * 4 + qi;
    const unsigned short* Qp = Qf + ((size_t)(bh * 64 + qgg) * 4) * 512 + lane * 8;
    bf16x8 qf[4];
#pragma unroll
    for (int kt = 0; kt < 4; ++kt)
        qf[kt] = *(const bf16x8*)(Qp + kt * 512);

    f32x16 zero;
#pragma unroll
    for (int r = 0; r < 16; ++r) zero[r] = 0.f;

    float lpart = 0.f;
    f32x16 Ot[2];
    Ot[0] = zero; Ot[1] = zero;

    bf16x8 kc[4];
#pragma unroll
    for (int c = 0; c < 4; ++c)
        kc[c] = *(const bf16x8*)(Kp + c * 512);

    for (int jt = 0; jt < 32; ++jt) {
        // V frags for this tile+half (consumed after exp -> latency hidden)
        bf16x8 vc[4];
#pragma unroll
        for (int dg = 0; dg < 2; ++dg)
#pragma unroll
            for (int p = 0; p < 2; ++p)
                vc[dg * 2 + p] = *(const bf16x8*)(
                    Vp + (size_t)jt * 4096 + (dg * 4 + jh * 2 + p) * 512);

        // S^T for this wave's q-group
        f32x16 st = zero;
        __builtin_amdgcn_s_setprio(1);
#pragma unroll
        for (int kt = 0; kt < 4; ++kt)
            st = __builtin_amdgcn_mfma_f32_32x32x16_bf16(kc[kt], qf[kt], st, 0, 0, 0);
        __builtin_amdgcn_s_setprio(0);

        // K prefetch for next tile
        const int jn = (jt < 31) ? jt + 1 : 31;
#pragma unroll
        for (int c = 0; c < 4; ++c)
            kc[c] = *(const bf16x8*)(Kp + (size_t)jn * 4096 + c * 512);

        // p = 2^s (no max subtraction; logits bounded); tree-summed l
#pragma unroll
        for (int r = 0; r < 16; ++r)
            st[r] = __builtin_amdgcn_exp2f(st[r]);
        {
            float s01 = st[0] + st[1],   s23 = st[2] + st[3];
            float s45 = st[4] + st[5],   s67 = st[6] + st[7];
            float s89 = st[8] + st[9],   sAB = st[10] + st[11];
            float sCD = st[12] + st[13], sEF = st[14] + st[15];
            lpart += ((s01 + s23) + (s45 + s67)) + ((s89 + sAB) + (sCD + sEF));
        }

        // P^T -> B-frag: cvt_pk (RNE) + permlane32_swap half-exchange (T12).
        // swap(D=a0,S=b0): D = lane<32 ? a0 : b0[l-32]; S = lane<32 ? a0[l+32] : b0
        // == exactly the frag words u[0], u[2].
#pragma unroll
        for (int p = 0; p < 2; ++p) {
            const int r0 = p * 8;
            unsigned a0, a1, b0, b1;
            asm("v_cvt_pk_bf16_f32 %0, %1, %2"
                : "=v"(a0) : "v"(st[r0 + 0]), "v"(st[r0 + 1]));
            asm("v_cvt_pk_bf16_f32 %0, %1, %2"
                : "=v"(a1) : "v"(st[r0 + 2]), "v"(st[r0 + 3]));
            asm("v_cvt_pk_bf16_f32 %0, %1, %2"
                : "=v"(b0) : "v"(st[r0 + 4]), "v"(st[r0 + 5]));
            asm("v_cvt_pk_bf16_f32 %0, %1, %2"
                : "=v"(b1) : "v"(st[r0 + 6]), "v"(st[r0 + 7]));
            asm("v_permlane32_swap_b32 %0, %1" : "+v"(a0), "+v"(b0));
            asm("v_permlane32_swap_b32 %0, %1" : "+v"(a1), "+v"(b1));
            union { unsigned u[4]; bf16x8 v; } pb;
            pb.u[0] = a0;
            pb.u[1] = a1;
            pb.u[2] = b0;
            pb.u[3] = b1;
            __builtin_amdgcn_s_setprio(1);
            Ot[0] = __builtin_amdgcn_mfma_f32_32x32x16_bf16(vc[0 + p], pb.v, Ot[0], 0, 0, 0);
            Ot[1] = __builtin_amdgcn_mfma_f32_32x32x16_bf16(vc[2 + p], pb.v, Ot[1], 0, 0, 0);
            __builtin_amdgcn_s_setprio(0);
        }
    }

    // ---- merge (O, l) across the jh pair; jh=0 stores ----
    if (jh == 1) {
#pragma unroll
        for (int dg = 0; dg < 2; ++dg) {
            const int cidx = (qi * 2 + dg) * 4;
#pragma unroll
            for (int k = 0; k < 4; ++k) {
                float4 v = make_float4(
                    Ot[dg][k * 4 + 0], Ot[dg][k * 4 + 1],
                    Ot[dg][k * 4 + 2], Ot[dg][k * 4 + 3]);
                *(float4*)(cb + (cidx + k) * 256 + lane * 4) = v;
            }
        }
        cb[8192 + qi * 64 + lane] = lpart;
    }
    __syncthreads();
    if (jh == 0) {
        const int bi = bh >> 3, h = bh & 7;
#pragma unroll
        for (int dg = 0; dg < 2; ++dg) {
            const int cidx = (qi * 2 + dg) * 4;
#pragma unroll
            for (int k = 0; k < 4; ++k) {
                const float4 v = *(const float4*)(cb + (cidx + k) * 256 + lane * 4);
                Ot[dg][k * 4 + 0] += v.x;
                Ot[dg][k * 4 + 1] += v.y;
                Ot[dg][k * 4 + 2] += v.z;
                Ot[dg][k * 4 + 3] += v.w;
            }
        }
        float lv = lpart + cb[8192 + qi * 64 + lane];
        lv += __shfl_xor(lv, 32);
        const float inv = 1.0f / (lv * 22.627416997969522f);

        const int ns = q0 + qi * 32 + l31;
        unsigned short* dst = Ow + ((size_t)bi * SEQ + ns) * 512 + h * 64 + hlf * 4;
#pragma unroll
        for (int dg = 0; dg < 2; ++dg)
#pragma unroll
            for (int rb2 = 0; rb2 < 4; ++rb2) {
                uint2 pk;
                pk.x = packbf(Ot[dg][rb2 * 4 + 0] * inv,
                              Ot[dg][rb2 * 4 + 1] * inv);
                pk.y = packbf(Ot[dg][rb2 * 4 + 2] * inv,
                              Ot[dg][rb2 * 4 + 3] * inv);
                *(uint2*)(dst + dg * 32 + rb2 * 8) = pk;
            }
    }
}

// ---------------------------------------------------------------------------
extern "C" void kernel_launch(void* const* d_in, const int* in_sizes, int n_in,
                              void* d_out, int out_size, void* d_ws, size_t ws_size,
                              hipStream_t stream)
{
    const float* x  = (const float*)d_in[0];
    const float* Wq = (const float*)d_in[1];
    const float* bq = (const float*)d_in[2];
    const float* Wk = (const float*)d_in[3];
    const float* bk = (const float*)d_in[4];
    const float* Wv = (const float*)d_in[5];
    const float* bv = (const float*)d_in[6];
    const float* Wp = (const float*)d_in[7];
    const float* bp = (const float*)d_in[8];

    unsigned short* ws = (unsigned short*)d_ws;
    unsigned short* Qw  = ws;                  // Q' frag-linear, *log2e (8 MB)
    unsigned short* Kw  = Qw + 4194304;        // K' frag-linear
    unsigned short* VTw = Kw + 4194304;        // V' frag-linear
    unsigned short* Owb = VTw + 4194304;       // [b][ns][512] bf16

    qkv_kernel<<<dim3(12, 64), 256, 0, stream>>>(
        x, Wq, Wk, Wv, bq, bk, bv, Qw, Kw, VTw);
    attn_kernel<<<dim3(32, 16), 512, 0, stream>>>(Qw, Kw, VTw, Owb);
    outproj_kernel<<<dim3(8, 64), 256, 0, stream>>>(Owb, Wp, bp, (float*)d_out);
}